// Round 1
// baseline (631.832 us; speedup 1.0000x reference)
//
#include <hip/hip_runtime.h>
#include <stdint.h>

// Problem constants
#define E_ 64
#define H_ 1024
#define I_ 768
#define T_ 8192

typedef __attribute__((ext_vector_type(4))) float floatx4;
typedef __attribute__((ext_vector_type(8))) short bf16x8;

__device__ inline unsigned short f2bf(float f) {
  union { float f; uint32_t u; } v; v.f = f;
  return (unsigned short)((v.u + 0x7FFFu + ((v.u >> 16) & 1u)) >> 16); // RNE
}
__device__ inline float bf2f(unsigned short s) {
  union { uint32_t u; float f; } v; v.u = ((uint32_t)s) << 16;
  return v.f;
}

// async global->LDS, 16B per lane. LDS dest must be wave-uniform base + lane*16.
__device__ inline void gload16(const void* g, void* l) {
  __builtin_amdgcn_global_load_lds(
      (const __attribute__((address_space(1))) void*)g,
      (__attribute__((address_space(3))) void*)l, 16, 0, 0);
}

// ---------------- prep: x fp32 -> bf16, and expert prefix offsets ----------------
__global__ void k_prep(const float* __restrict__ x, unsigned short* __restrict__ xb,
                       const int* __restrict__ cnts, int* __restrict__ offs) {
  int i = blockIdx.x * 256 + threadIdx.x;  // 4 elems per thread, T_*H_/4 threads exactly
  float4 v = ((const float4*)x)[i];
  ushort4 o;
  o.x = f2bf(v.x); o.y = f2bf(v.y); o.z = f2bf(v.z); o.w = f2bf(v.w);
  ((ushort4*)xb)[i] = o;
  if (i == 0) {
    int s = 0; offs[0] = 0;
    for (int e = 0; e < E_; ++e) { s += cnts[e]; offs[e + 1] = s; }
  }
}

// ---------------- GEMM1: gate/up fused + SwiGLU -> h (bf16) ----------------
// block tile: 256 rows x 64 cols, K = 1024, BK = 32. 4 waves, wave w owns rows [w*64, w*64+64).
// Waves beyond the expert's count skip compute (weights still read exactly once per expert).
__global__ __launch_bounds__(256, 2) void k_gemm1(
    const unsigned short* __restrict__ xb, const float* __restrict__ w1,
    const float* __restrict__ w3, unsigned short* __restrict__ h,
    const int* __restrict__ offs) {
  __shared__ unsigned short As[256 * 32];  // [m][k] bf16, row stride 64B (2-way = free)
  __shared__ float Bs1[32 * 64];           // [k][n] fp32 (as loaded; transpose at frag build)
  __shared__ float Bs3[32 * 64];

  const int tid = threadIdx.x;
  const int wv = tid >> 6;
  const int l = tid & 63;
  const int lq = l >> 4;   // quad
  const int ln = l & 15;
  const int e = blockIdx.x / (I_ / 64);
  const int n0 = (blockIdx.x % (I_ / 64)) * 64;
  const int off = offs[e];
  const int cnt = offs[e + 1] - off;

  // B staging source: thread t covers k-row (tid>>4) (+16 on 2nd round), 16B of n
  const float* b1p = w1 + (size_t)e * (H_ * I_) + (size_t)(tid >> 4) * I_ + n0 + (tid & 15) * 4;
  const float* b3p = w3 + (size_t)e * (H_ * I_) + (size_t)(tid >> 4) * I_ + n0 + (tid & 15) * 4;
  unsigned short* aDst = &As[tid * 8];   // bytes tid*16; round adds 4096B
  float* b1Dst = &Bs1[tid * 4];          // bytes tid*16; round adds 4096B
  float* b3Dst = &Bs3[tid * 4];

  for (int mb = 0; mb < cnt; mb += 256) {
    const int m_here = (cnt - mb) < 256 ? (cnt - mb) : 256;
    const bool active = (wv * 64) < m_here;

    const unsigned short* aptr[4];
#pragma unroll
    for (int r = 0; r < 4; ++r) {
      int row = off + mb + r * 64 + (tid >> 2);
      row = row < (T_ - 1) ? row : (T_ - 1);  // clamp; garbage rows masked at store
      aptr[r] = xb + (size_t)row * H_ + (tid & 3) * 8;
    }

    floatx4 accG[4][4], accU[4][4];
#pragma unroll
    for (int i2 = 0; i2 < 4; ++i2)
#pragma unroll
      for (int j2 = 0; j2 < 4; ++j2) {
        accG[i2][j2] = (floatx4){0.f, 0.f, 0.f, 0.f};
        accU[i2][j2] = (floatx4){0.f, 0.f, 0.f, 0.f};
      }

    for (int kt = 0; kt < H_ / 32; ++kt) {
      __syncthreads();  // previous tile's consumers done
#pragma unroll
      for (int r = 0; r < 4; ++r)
        gload16(aptr[r] + kt * 32, aDst + r * 2048);
#pragma unroll
      for (int r = 0; r < 2; ++r) {
        gload16(b1p + (size_t)(kt * 32 + r * 16) * I_, b1Dst + r * 1024);
        gload16(b3p + (size_t)(kt * 32 + r * 16) * I_, b3Dst + r * 1024);
      }
      __syncthreads();  // waits vmcnt(0): staged data visible

      if (active) {
        bf16x8 bG[4], bU[4];
#pragma unroll
        for (int nf = 0; nf < 4; ++nf) {
          const float* p1 = &Bs1[(lq * 8) * 64 + nf * 16 + ln];
          const float* p3 = &Bs3[(lq * 8) * 64 + nf * 16 + ln];
          bf16x8 t1, t3;
#pragma unroll
          for (int j = 0; j < 8; ++j) {
            t1[j] = (short)f2bf(p1[j * 64]);
            t3[j] = (short)f2bf(p3[j * 64]);
          }
          bG[nf] = t1; bU[nf] = t3;
        }
#pragma unroll
        for (int mf = 0; mf < 4; ++mf) {
          const bf16x8 af = *(const bf16x8*)&As[(size_t)(wv * 64 + mf * 16 + ln) * 32 + lq * 8];
#pragma unroll
          for (int nf = 0; nf < 4; ++nf) {
            accG[mf][nf] = __builtin_amdgcn_mfma_f32_16x16x32_bf16(af, bG[nf], accG[mf][nf], 0, 0, 0);
            accU[mf][nf] = __builtin_amdgcn_mfma_f32_16x16x32_bf16(af, bU[nf], accU[mf][nf], 0, 0, 0);
          }
        }
      }
    }

    if (active) {
#pragma unroll
      for (int mf = 0; mf < 4; ++mf)
#pragma unroll
        for (int nf = 0; nf < 4; ++nf)
#pragma unroll
          for (int r = 0; r < 4; ++r) {
            int row_l = wv * 64 + mf * 16 + lq * 4 + r;  // C/D: row=quad*4+reg, col=lane&15
            if (row_l < m_here) {
              float g = bf2f(f2bf(accG[mf][nf][r]));  // match ref: gate/up rounded to bf16
              float u = bf2f(f2bf(accU[mf][nf][r]));
              float hv = (g / (1.0f + __expf(-g))) * u;  // silu(g)*u
              h[(size_t)(off + mb + row_l) * I_ + n0 + nf * 16 + ln] = f2bf(hv);
            }
          }
    }
  }
}

// ---------------- GEMM2: out = h @ w2 (fp32 out) ----------------
__global__ __launch_bounds__(256, 2) void k_gemm2(
    const unsigned short* __restrict__ h, const float* __restrict__ w2,
    float* __restrict__ out, const int* __restrict__ offs) {
  __shared__ unsigned short As[256 * 32];
  __shared__ float Bs[32 * 64];

  const int tid = threadIdx.x;
  const int wv = tid >> 6;
  const int l = tid & 63;
  const int lq = l >> 4;
  const int ln = l & 15;
  const int e = blockIdx.x / (H_ / 64);
  const int n0 = (blockIdx.x % (H_ / 64)) * 64;
  const int off = offs[e];
  const int cnt = offs[e + 1] - off;

  const float* b2p = w2 + (size_t)e * (I_ * H_) + (size_t)(tid >> 4) * H_ + n0 + (tid & 15) * 4;
  unsigned short* aDst = &As[tid * 8];
  float* bDst = &Bs[tid * 4];

  for (int mb = 0; mb < cnt; mb += 256) {
    const int m_here = (cnt - mb) < 256 ? (cnt - mb) : 256;
    const bool active = (wv * 64) < m_here;

    const unsigned short* aptr[4];
#pragma unroll
    for (int r = 0; r < 4; ++r) {
      int row = off + mb + r * 64 + (tid >> 2);
      row = row < (T_ - 1) ? row : (T_ - 1);
      aptr[r] = h + (size_t)row * I_ + (tid & 3) * 8;
    }

    floatx4 acc[4][4];
#pragma unroll
    for (int i2 = 0; i2 < 4; ++i2)
#pragma unroll
      for (int j2 = 0; j2 < 4; ++j2) acc[i2][j2] = (floatx4){0.f, 0.f, 0.f, 0.f};

    for (int kt = 0; kt < I_ / 32; ++kt) {
      __syncthreads();
#pragma unroll
      for (int r = 0; r < 4; ++r)
        gload16(aptr[r] + kt * 32, aDst + r * 2048);
#pragma unroll
      for (int r = 0; r < 2; ++r)
        gload16(b2p + (size_t)(kt * 32 + r * 16) * H_, bDst + r * 1024);
      __syncthreads();

      if (active) {
        bf16x8 bF[4];
#pragma unroll
        for (int nf = 0; nf < 4; ++nf) {
          const float* p = &Bs[(lq * 8) * 64 + nf * 16 + ln];
          bf16x8 t;
#pragma unroll
          for (int j = 0; j < 8; ++j) t[j] = (short)f2bf(p[j * 64]);
          bF[nf] = t;
        }
#pragma unroll
        for (int mf = 0; mf < 4; ++mf) {
          const bf16x8 af = *(const bf16x8*)&As[(size_t)(wv * 64 + mf * 16 + ln) * 32 + lq * 8];
#pragma unroll
          for (int nf = 0; nf < 4; ++nf)
            acc[mf][nf] = __builtin_amdgcn_mfma_f32_16x16x32_bf16(af, bF[nf], acc[mf][nf], 0, 0, 0);
        }
      }
    }

    if (active) {
#pragma unroll
      for (int mf = 0; mf < 4; ++mf)
#pragma unroll
        for (int nf = 0; nf < 4; ++nf)
#pragma unroll
          for (int r = 0; r < 4; ++r) {
            int row_l = wv * 64 + mf * 16 + lq * 4 + r;
            if (row_l < m_here)
              out[(size_t)(off + mb + row_l) * H_ + n0 + nf * 16 + ln] = acc[mf][nf][r];
          }
    }
  }
}

extern "C" void kernel_launch(void* const* d_in, const int* in_sizes, int n_in,
                              void* d_out, int out_size, void* d_ws, size_t ws_size,
                              hipStream_t stream) {
  const float* x  = (const float*)d_in[0];
  const float* w1 = (const float*)d_in[1];
  const float* w2 = (const float*)d_in[2];
  const float* w3 = (const float*)d_in[3];
  const int* cnts = (const int*)d_in[4];
  float* out = (float*)d_out;

  char* ws = (char*)d_ws;
  int* offs = (int*)ws;                                        // 65 ints
  unsigned short* xb = (unsigned short*)(ws + 1024);           // 16 MB  (T_*H_ bf16)
  unsigned short* h  = (unsigned short*)(ws + 1024 + (size_t)T_ * H_ * 2);  // 12 MB (T_*I_ bf16)

  k_prep<<<(T_ * H_) / (256 * 4), 256, 0, stream>>>(x, xb, cnts, offs);
  k_gemm1<<<E_ * (I_ / 64), 256, 0, stream>>>(xb, w1, w3, h, offs);
  k_gemm2<<<E_ * (H_ / 64), 256, 0, stream>>>(h, w2, out, offs);
}